// Round 15
// baseline (573.909 us; speedup 1.0000x reference)
//
#include <hip/hip_runtime.h>

#define IMW 64
#define HW 4096
#define BATCH 64
#define NPIX (BATCH * HW)   // 262144
#define TPB 512             // threads per spatial block
#define PIXBLK 8            // pixel-blocks per image (4096/512)
#define BN_EPS 1e-5f

// ---------------- bf16 helpers (manual, RNE) ----------------
__device__ inline float bfbits(unsigned int hi16) {
    union { unsigned int i; float f; } v; v.i = hi16; return v.f;
}
__device__ inline float bf_lo(unsigned int u) { return bfbits(u << 16); }
__device__ inline float bf_hi(unsigned int u) { return bfbits(u & 0xffff0000u); }
__device__ inline unsigned short f2bf(float f) {
    union { float f; unsigned int i; } v; v.f = f;
    unsigned int i = v.i;
    i += 0x7fff + ((i >> 16) & 1);
    return (unsigned short)(i >> 16);
}

// ---------------- fp16 helpers ----------------
__device__ inline unsigned pack_h2(float a, float b) {
    union { unsigned u; _Float16 h[2]; } v;
    v.h[0] = (_Float16)a;
    v.h[1] = (_Float16)b;
    return v.u;
}
__device__ inline float h_lo(unsigned u) {
    union { unsigned u; _Float16 h[2]; } v; v.u = u; return (float)v.h[0];
}
__device__ inline float h_hi(unsigned u) {
    union { unsigned u; _Float16 h[2]; } v; v.u = u; return (float)v.h[1];
}
__device__ inline unsigned short f2h(float f) {
    union { _Float16 h; unsigned short u; } v; v.h = (_Float16)f; return v.u;
}

// ---------------------------------------------------------------------------
// XCD-pinned swizzle (verified R3). XCD = lin & 7 owns images [8*xcd,8*xcd+8).
// ---------------------------------------------------------------------------
template <int CO_BLOCKS>
__device__ inline void swz(int lin, int& img, int& xblk, int& cob) {
    const int per_img = PIXBLK * CO_BLOCKS;
    int xcd = lin & 7;
    int s = lin >> 3;
    img = xcd * 8 + s / per_img;
    int r = s % per_img;
    cob = r / PIXBLK;
    xblk = r % PIXBLK;
}

// ---------------------------------------------------------------------------
// Direct 3x3 conv, pad=1 (unchanged from R14).
// ---------------------------------------------------------------------------
template <int CIN, int COUT, bool RELU, bool BIAS, bool AFF, bool IN_NCHW,
          bool IN_BF16, int OUT_MODE, bool FUSE_BN>
__global__ void conv3x3_k(const void* __restrict__ in_,
                          const float* __restrict__ w,
                          const float* __restrict__ bias,
                          const float* __restrict__ isums,
                          const float* __restrict__ ig,
                          const float* __restrict__ ib_,
                          void* __restrict__ out_,
                          float* __restrict__ bnsums) {
    __shared__ float lw[9 * CIN * COUT];
    __shared__ float lb[COUT];
    __shared__ float lsc[CIN];
    __shared__ float lsh[CIN];
    __shared__ float bnacc[FUSE_BN ? 2 * COUT : 1];

    for (int dst = threadIdx.x; dst < 9 * CIN * COUT; dst += blockDim.x) {
        int co = dst % COUT;
        int kci = dst / COUT;
        int k = kci / CIN;
        int ci = kci % CIN;
        lw[dst] = w[(size_t)co * (CIN * 9) + ci * 9 + k];
    }
    if (threadIdx.x < COUT) lb[threadIdx.x] = BIAS ? bias[threadIdx.x] : 0.f;
    if (AFF && threadIdx.x < CIN) {
        const float invN = 1.f / (float)NPIX;
        float mean = isums[threadIdx.x] * invN;
        float var = isums[CIN + threadIdx.x] * invN - mean * mean;
        float sc = ig[threadIdx.x] * rsqrtf(var + BN_EPS);
        lsc[threadIdx.x] = sc;
        lsh[threadIdx.x] = ib_[threadIdx.x] - mean * sc;
    }
    if (FUSE_BN && threadIdx.x < 2 * COUT) bnacc[threadIdx.x] = 0.f;
    __syncthreads();

    int img, xblk, cob;
    swz<1>(blockIdx.x, img, xblk, cob);
    int b = img;
    int pos = xblk * TPB + threadIdx.x;
    int p = (b << 12) + pos;
    int y = pos >> 6;
    int x = pos & 63;

    float acc[COUT];
#pragma unroll
    for (int co = 0; co < COUT; ++co) acc[co] = lb[co];

#pragma unroll 1
    for (int k = 0; k < 9; ++k) {
        int ky = k / 3, kx = k - ky * 3;
        int yy = y + ky - 1, xx = x + kx - 1;
        if (yy < 0 || yy >= IMW || xx < 0 || xx >= IMW) continue;

        float vin[CIN];
        if constexpr (IN_NCHW) {
            const float* ip = (const float*)in_;
#pragma unroll
            for (int ci = 0; ci < CIN; ++ci)
                vin[ci] = ip[((size_t)(b * CIN + ci) << 12) + yy * IMW + xx];
        } else if constexpr (!IN_BF16) {
            const float* ip = (const float*)in_ + ((size_t)((b << 12) + yy * IMW + xx)) * CIN;
#pragma unroll
            for (int c4 = 0; c4 < CIN / 4; ++c4) {
                float4 v = *(const float4*)(ip + c4 * 4);
                vin[c4 * 4 + 0] = v.x;
                vin[c4 * 4 + 1] = v.y;
                vin[c4 * 4 + 2] = v.z;
                vin[c4 * 4 + 3] = v.w;
            }
        } else if constexpr (CIN % 8 == 0) {
            const uint4* ip = (const uint4*)((const unsigned short*)in_ +
                                             ((size_t)((b << 12) + yy * IMW + xx)) * CIN);
#pragma unroll
            for (int c8 = 0; c8 < CIN / 8; ++c8) {
                uint4 u = ip[c8];
                vin[c8 * 8 + 0] = bf_lo(u.x); vin[c8 * 8 + 1] = bf_hi(u.x);
                vin[c8 * 8 + 2] = bf_lo(u.y); vin[c8 * 8 + 3] = bf_hi(u.y);
                vin[c8 * 8 + 4] = bf_lo(u.z); vin[c8 * 8 + 5] = bf_hi(u.z);
                vin[c8 * 8 + 6] = bf_lo(u.w); vin[c8 * 8 + 7] = bf_hi(u.w);
            }
        } else {
            const uint2* ip = (const uint2*)((const unsigned short*)in_ +
                                             ((size_t)((b << 12) + yy * IMW + xx)) * CIN);
#pragma unroll
            for (int c4 = 0; c4 < CIN / 4; ++c4) {
                uint2 u = ip[c4];
                vin[c4 * 4 + 0] = bf_lo(u.x); vin[c4 * 4 + 1] = bf_hi(u.x);
                vin[c4 * 4 + 2] = bf_lo(u.y); vin[c4 * 4 + 3] = bf_hi(u.y);
            }
        }
        if constexpr (AFF) {
#pragma unroll
            for (int ci = 0; ci < CIN; ++ci)
                vin[ci] = fmaf(vin[ci], lsc[ci], lsh[ci]);
        }
#pragma unroll
        for (int ci = 0; ci < CIN; ++ci) {
            float s = vin[ci];
            const float* wr = &lw[(k * CIN + ci) * COUT];
#pragma unroll
            for (int co = 0; co < COUT; ++co)
                acc[co] = fmaf(wr[co], s, acc[co]);
        }
    }

    if (RELU) {
#pragma unroll
        for (int co = 0; co < COUT; ++co) acc[co] = fmaxf(acc[co], 0.f);
    }

    if constexpr (FUSE_BN) {
#pragma unroll
        for (int co = 0; co < COUT; ++co) {
            float s = acc[co];
            float q = s * s;
#pragma unroll
            for (int off = 32; off; off >>= 1) {
                s += __shfl_down(s, off, 64);
                q += __shfl_down(q, off, 64);
            }
            if ((threadIdx.x & 63) == 0) {
                atomicAdd(&bnacc[co], s);
                atomicAdd(&bnacc[COUT + co], q);
            }
        }
    }

    if constexpr (OUT_MODE == 2) {
        unsigned* o = (unsigned*)out_;
#pragma unroll
        for (int i = 0; i < COUT / 2; ++i)
            o[(size_t)i * NPIX + p] = pack_h2(acc[2 * i], acc[2 * i + 1]);
    } else if constexpr (OUT_MODE == 1) {
        unsigned int us[COUT / 2];
#pragma unroll
        for (int i = 0; i < COUT / 2; ++i)
            us[i] = (unsigned int)f2bf(acc[2 * i]) | ((unsigned int)f2bf(acc[2 * i + 1]) << 16);
        uint2* o2 = (uint2*)((unsigned short*)out_ + (size_t)p * COUT);
#pragma unroll
        for (int i = 0; i < COUT / 4; ++i)
            o2[i] = make_uint2(us[2 * i], us[2 * i + 1]);
    } else {
        float* op = (float*)out_ + (size_t)p * COUT;
        if constexpr (COUT % 4 == 0) {
#pragma unroll
            for (int c4 = 0; c4 < COUT / 4; ++c4)
                *(float4*)(op + c4 * 4) =
                    make_float4(acc[c4 * 4], acc[c4 * 4 + 1], acc[c4 * 4 + 2], acc[c4 * 4 + 3]);
        } else {
#pragma unroll
            for (int c2 = 0; c2 < COUT / 2; ++c2)
                *(float2*)(op + c2 * 2) = make_float2(acc[c2 * 2], acc[c2 * 2 + 1]);
        }
    }

    if constexpr (FUSE_BN) {
        __syncthreads();
        if (threadIdx.x < 2 * COUT)
            atomicAdd(&bnsums[threadIdx.x], bnacc[threadIdx.x]);
    }
}

// ---------------------------------------------------------------------------
// deform1 (R7-proven two-pass): bf16 NHWC in + fp16 plane offsets,
// full 9-tap LDS weights, fused BN stats. Unchanged from R14.
// ---------------------------------------------------------------------------
template <int CIN, int COUT_TOT, int COUT_BLK, int CO_BLOCKS>
__global__ void deform_k(const void* __restrict__ in_,
                         const unsigned* __restrict__ off,
                         const float* __restrict__ w,
                         const float* __restrict__ isums,
                         const float* __restrict__ ig,
                         const float* __restrict__ ib_,
                         void* __restrict__ out_,
                         float* __restrict__ bnsums) {
    __shared__ float lw[9 * CIN * COUT_BLK];
    __shared__ float lsc[CIN];
    __shared__ float lsh[CIN];
    __shared__ float bnacc[2 * COUT_BLK];

    int img, xblk, cob;
    swz<CO_BLOCKS>(blockIdx.x, img, xblk, cob);
    int co_base = cob * COUT_BLK;

    if (threadIdx.x < CIN) {
        const float invN = 1.f / (float)NPIX;
        float mean = isums[threadIdx.x] * invN;
        float var = isums[CIN + threadIdx.x] * invN - mean * mean;
        float sc = ig[threadIdx.x] * rsqrtf(var + BN_EPS);
        lsc[threadIdx.x] = sc;
        lsh[threadIdx.x] = ib_[threadIdx.x] - mean * sc;
    }
    if (threadIdx.x < 2 * COUT_BLK) bnacc[threadIdx.x] = 0.f;

    for (int dst = threadIdx.x; dst < 9 * CIN * COUT_BLK; dst += blockDim.x) {
        int co = dst % COUT_BLK;
        int kci = dst / COUT_BLK;
        int k = kci / CIN;
        int ci = kci % CIN;
        lw[dst] = w[(size_t)(co_base + co) * (CIN * 9) + ci * 9 + k];
    }
    __syncthreads();

    int b = img;
    int pos = xblk * TPB + threadIdx.x;
    int p = (b << 12) + pos;
    int y = pos >> 6;
    int x = pos & 63;

    float acc[COUT_BLK];
#pragma unroll
    for (int co = 0; co < COUT_BLK; ++co) acc[co] = 0.f;

    unsigned od[9];
#pragma unroll
    for (int j = 0; j < 9; ++j) od[j] = off[(size_t)j * NPIX + p];

    const unsigned short* ib = (const unsigned short*)in_ + (size_t)b * HW * CIN;

#pragma unroll 1
    for (int k = 0; k < 9; ++k) {
        int ky = k / 3, kx = k - ky * 3;
        float py = (float)(y + ky - 1) + h_lo(od[k]);
        float px = (float)(x + kx - 1) + h_hi(od[k]);
        float fy = floorf(py), fx = floorf(px);
        float wy = py - fy, wx = px - fx;
        int y0 = (int)fy, x0 = (int)fx;
        int y1 = y0 + 1, x1 = x0 + 1;
        bool vy0 = (unsigned)y0 < (unsigned)IMW;
        bool vy1 = (unsigned)y1 < (unsigned)IMW;
        bool vx0 = (unsigned)x0 < (unsigned)IMW;
        bool vx1 = (unsigned)x1 < (unsigned)IMW;
        int cy0 = min(max(y0, 0), IMW - 1), cy1 = min(max(y1, 0), IMW - 1);
        int cx0 = min(max(x0, 0), IMW - 1), cx1 = min(max(x1, 0), IMW - 1);
        float w00 = (1.f - wy) * (1.f - wx) * ((vy0 & vx0) ? 1.f : 0.f);
        float w01 = (1.f - wy) * wx * ((vy0 & vx1) ? 1.f : 0.f);
        float w10 = wy * (1.f - wx) * ((vy1 & vx0) ? 1.f : 0.f);
        float w11 = wy * wx * ((vy1 & vx1) ? 1.f : 0.f);
        float wsum = w00 + w01 + w10 + w11;

        const uint2* q00 = (const uint2*)(ib + (size_t)(cy0 * IMW + cx0) * CIN);
        const uint2* q01 = (const uint2*)(ib + (size_t)(cy0 * IMW + cx1) * CIN);
        const uint2* q10 = (const uint2*)(ib + (size_t)(cy1 * IMW + cx0) * CIN);
        const uint2* q11 = (const uint2*)(ib + (size_t)(cy1 * IMW + cx1) * CIN);
#pragma unroll
        for (int c4 = 0; c4 < CIN / 4; ++c4) {
            uint2 a = q00[c4], bq = q01[c4], c = q10[c4], d = q11[c4];
#pragma unroll
            for (int h = 0; h < 2; ++h) {
                unsigned int ua = (&a.x)[h], ub = (&bq.x)[h];
                unsigned int uc = (&c.x)[h], ud = (&d.x)[h];
                int ci0 = c4 * 4 + h * 2;
                float r0 = w00 * bf_lo(ua) + w01 * bf_lo(ub) +
                           w10 * bf_lo(uc) + w11 * bf_lo(ud);
                float r1 = w00 * bf_hi(ua) + w01 * bf_hi(ub) +
                           w10 * bf_hi(uc) + w11 * bf_hi(ud);
                float s0 = fmaf(r0, lsc[ci0], lsh[ci0] * wsum);
                float s1 = fmaf(r1, lsc[ci0 + 1], lsh[ci0 + 1] * wsum);
                const float* wr0 = &lw[(k * CIN + ci0) * COUT_BLK];
                const float* wr1 = &lw[(k * CIN + ci0 + 1) * COUT_BLK];
#pragma unroll
                for (int co = 0; co < COUT_BLK; ++co)
                    acc[co] = fmaf(wr0[co], s0, acc[co]);
#pragma unroll
                for (int co = 0; co < COUT_BLK; ++co)
                    acc[co] = fmaf(wr1[co], s1, acc[co]);
            }
        }
    }

#pragma unroll
    for (int co = 0; co < COUT_BLK; ++co) acc[co] = fmaxf(acc[co], 0.f);

#pragma unroll
    for (int co = 0; co < COUT_BLK; ++co) {
        float s = acc[co];
        float q = s * s;
#pragma unroll
        for (int off2 = 32; off2; off2 >>= 1) {
            s += __shfl_down(s, off2, 64);
            q += __shfl_down(q, off2, 64);
        }
        if ((threadIdx.x & 63) == 0) {
            atomicAdd(&bnacc[co], s);
            atomicAdd(&bnacc[COUT_BLK + co], q);
        }
    }

    unsigned int us[COUT_BLK / 2];
#pragma unroll
    for (int i = 0; i < COUT_BLK / 2; ++i)
        us[i] = (unsigned int)f2bf(acc[2 * i]) | ((unsigned int)f2bf(acc[2 * i + 1]) << 16);
    unsigned short* ob = (unsigned short*)out_ + (size_t)p * COUT_TOT + co_base;
    uint2* o2 = (uint2*)ob;
#pragma unroll
    for (int i = 0; i < COUT_BLK / 4; ++i)
        o2[i] = make_uint2(us[2 * i], us[2 * i + 1]);

    __syncthreads();
    if (threadIdx.x < COUT_BLK)
        atomicAdd(&bnsums[co_base + threadIdx.x], bnacc[threadIdx.x]);
    else if (threadIdx.x < 2 * COUT_BLK)
        atomicAdd(&bnsums[COUT_TOT + co_base + (threadIdx.x - COUT_BLK)],
                  bnacc[threadIdx.x]);
}

// ---------------------------------------------------------------------------
// R15: deform2 sample-once via lane-pairing. 512 thr = 8 waves x (32 pix x
// 2 co-halves); lanes l and l^32 share a pixel. Each thread gathers 20 of 40
// channels (2 uint4 + 1 uint2 per corner, per-half aligned offsets), does
// bilinear+affine for them, FMAs into acc[32], then pulls the partner's 20
// samples via __shfl_xor(.,32) group-wise (<=8 floats live). Gather bytes and
// bilinear VALU halve vs the R7 two-pass config; acc stays 32 (no VGPR cliff).
// Weights per-tap double-buffered (R7-proven barrier pattern).
// ---------------------------------------------------------------------------
__global__ void deform2_pair_k(const unsigned short* __restrict__ in_, // h3 bf16 NHWC
                               const unsigned* __restrict__ off,       // fp16 planes
                               const float* __restrict__ w,            // wd2 [64][360]
                               const float* __restrict__ isums,
                               const float* __restrict__ ig,
                               const float* __restrict__ ib_,
                               unsigned short* __restrict__ out_) {    // fp16 NCHW
    constexpr int CIN = 40;
    constexpr int WSLICE = CIN * 64;            // 2560 floats per tap
    __shared__ float lw[2 * WSLICE];            // 20.5 KB
    __shared__ float lsc[CIN], lsh[CIN];

    int lin = blockIdx.x;
    int xcd = lin & 7, sb = lin >> 3;
    int img = xcd * 8 + (sb >> 4);              // 16 blocks/image
    int xblk = sb & 15;

    int t = threadIdx.x;
    if (t < CIN) {
        const float invN = 1.f / (float)NPIX;
        float mean = isums[t] * invN;
        float var = isums[CIN + t] * invN - mean * mean;
        float sc = ig[t] * rsqrtf(var + BN_EPS);
        lsc[t] = sc;
        lsh[t] = ib_[t] - mean * sc;
    }

    // dst-linear weight staging: dst = r*512 + t -> co = t&63, ci = r*8 + (t>>6)
    const float* wsrc = w + (size_t)(t & 63) * (CIN * 9) + (t >> 6) * 9;
    auto stage_tap = [&](int k, int buf) {
        float* d = lw + buf * WSLICE + t;
#pragma unroll
        for (int j = 0; j < 5; ++j)
            d[j * 512] = wsrc[(size_t)j * 72 + k];
    };
    stage_tap(0, 0);
    __syncthreads();

    int half = (t >> 5) & 1;                    // co-half within wave
    int pixel = (t >> 6) * 32 + (t & 31);       // 0..255
    int pos = xblk * 256 + pixel;
    int p = (img << 12) + pos;
    int y = pos >> 6, x = pos & 63;

    float acc[32];
#pragma unroll
    for (int j = 0; j < 32; ++j) acc[j] = 0.f;

    unsigned od[9];
#pragma unroll
    for (int j = 0; j < 9; ++j) od[j] = off[(size_t)j * NPIX + p];

    const unsigned* ibd = (const unsigned*)(in_ + (size_t)img * HW * CIN);
    // per-half load offsets within a 20-dword corner (all 16B/8B aligned):
    //  half0: uint4@0, uint4@4, uint2@8   -> ch 0..19
    //  half1: uint4@12, uint4@16, uint2@10 -> ch 20..39 (u2 first in ch order)
    const int oQ = half * 12;                   // 0 or 12
    const int oU = 8 + half * 2;                // 8 or 10
    // channel bases (this thread / partner):
    const int cQ1 = half * 24;                  // q1: ch 0..7  | 24..31
    const int cQ2 = 8 + half * 24;              // q2: ch 8..15 | 32..39
    const int cU  = 16 + half * 4;              // u2: ch 16..19| 20..23
    const int pQ1 = (1 - half) * 24;
    const int pQ2 = 8 + (1 - half) * 24;
    const int pU  = 16 + (1 - half) * 4;
    const int cofs = half * 32;                 // my co range base in lw rows

#pragma unroll 1
    for (int k = 0; k < 9; ++k) {
        if (k < 8) stage_tap(k + 1, (k + 1) & 1);
        const float* lwk = lw + (k & 1) * WSLICE;

        int ky = k / 3, kx = k - ky * 3;
        float py = (float)(y + ky - 1) + h_lo(od[k]);
        float px = (float)(x + kx - 1) + h_hi(od[k]);
        float fy = floorf(py), fx = floorf(px);
        float wy = py - fy, wx = px - fx;
        int y0 = (int)fy, x0 = (int)fx;
        int y1 = y0 + 1, x1 = x0 + 1;
        bool vy0 = (unsigned)y0 < 64u, vy1 = (unsigned)y1 < 64u;
        bool vx0 = (unsigned)x0 < 64u, vx1 = (unsigned)x1 < 64u;
        int cy0 = min(max(y0, 0), 63), cy1 = min(max(y1, 0), 63);
        int cx0 = min(max(x0, 0), 63), cx1 = min(max(x1, 0), 63);
        float w00 = (1.f - wy) * (1.f - wx) * ((vy0 & vx0) ? 1.f : 0.f);
        float w01 = (1.f - wy) * wx * ((vy0 & vx1) ? 1.f : 0.f);
        float w10 = wy * (1.f - wx) * ((vy1 & vx0) ? 1.f : 0.f);
        float w11 = wy * wx * ((vy1 & vx1) ? 1.f : 0.f);
        float wsum = w00 + w01 + w10 + w11;

        const unsigned* p00 = ibd + (size_t)(cy0 * 64 + cx0) * 20;
        const unsigned* p01 = ibd + (size_t)(cy0 * 64 + cx1) * 20;
        const unsigned* p10 = ibd + (size_t)(cy1 * 64 + cx0) * 20;
        const unsigned* p11 = ibd + (size_t)(cy1 * 64 + cx1) * 20;

        // process one load-group: N dwords from each corner at dword-offset go,
        // own channels base cb, partner base pb
        auto group = [&](const unsigned* ga, const unsigned* gb,
                         const unsigned* gc, const unsigned* gd,
                         int n, int cb, int pb) {
            float sf[8];
#pragma unroll
            for (int d = 0; d < 4; ++d) {
                if (d >= n) break;
                unsigned ua = ga[d], ub = gb[d], uc = gc[d], ud = gd[d];
                float r0 = w00 * bf_lo(ua) + w01 * bf_lo(ub) +
                           w10 * bf_lo(uc) + w11 * bf_lo(ud);
                float r1 = w00 * bf_hi(ua) + w01 * bf_hi(ub) +
                           w10 * bf_hi(uc) + w11 * bf_hi(ud);
                int ci = cb + 2 * d;
                sf[2 * d]     = fmaf(r0, lsc[ci], lsh[ci] * wsum);
                sf[2 * d + 1] = fmaf(r1, lsc[ci + 1], lsh[ci + 1] * wsum);
            }
            // own FMAs
#pragma unroll
            for (int d = 0; d < 4; ++d) {
                if (d >= n) break;
#pragma unroll
                for (int e = 0; e < 2; ++e) {
                    float sv = sf[2 * d + e];
                    const float* wr = &lwk[(cb + 2 * d + e) * 64 + cofs];
#pragma unroll
                    for (int j = 0; j < 32; ++j)
                        acc[j] = fmaf(wr[j], sv, acc[j]);
                }
            }
            // partner FMAs (shfl one at a time; partner runs same code in lockstep)
#pragma unroll
            for (int d = 0; d < 4; ++d) {
                if (d >= n) break;
#pragma unroll
                for (int e = 0; e < 2; ++e) {
                    float pv = __shfl_xor(sf[2 * d + e], 32, 64);
                    const float* wr = &lwk[(pb + 2 * d + e) * 64 + cofs];
#pragma unroll
                    for (int j = 0; j < 32; ++j)
                        acc[j] = fmaf(wr[j], pv, acc[j]);
                }
            }
        };

        {   // group Q1: 4 dwords at oQ
            uint4 a = *(const uint4*)(p00 + oQ), b = *(const uint4*)(p01 + oQ);
            uint4 c = *(const uint4*)(p10 + oQ), d = *(const uint4*)(p11 + oQ);
            group(&a.x, &b.x, &c.x, &d.x, 4, cQ1, pQ1);
        }
        {   // group Q2: 4 dwords at oQ+4
            uint4 a = *(const uint4*)(p00 + oQ + 4), b = *(const uint4*)(p01 + oQ + 4);
            uint4 c = *(const uint4*)(p10 + oQ + 4), d = *(const uint4*)(p11 + oQ + 4);
            group(&a.x, &b.x, &c.x, &d.x, 4, cQ2, pQ2);
        }
        {   // group U: 2 dwords at oU
            uint2 a = *(const uint2*)(p00 + oU), b = *(const uint2*)(p01 + oU);
            uint2 c = *(const uint2*)(p10 + oU), d = *(const uint2*)(p11 + oU);
            group(&a.x, &b.x, &c.x, &d.x, 2, cU, pU);
        }

        __syncthreads();
    }

    // epilogue: relu + fp16 NCHW store (co = cofs + j)
#pragma unroll
    for (int j = 0; j < 32; ++j) {
        float v = fmaxf(acc[j], 0.f);
        __builtin_nontemporal_store(f2h(v),
            &out_[((size_t)(img * 64 + cofs + j) << 12) + pos]);
    }
}

// ---------------------------------------------------------------------------
// BN stats over fp16 NCHW raw em (dword-vectorized). 64 ch x 32 parts.
// ---------------------------------------------------------------------------
__global__ void bn_partial_nchw_h16(const unsigned short* __restrict__ raw,
                                    float* __restrict__ sums) {
    const int parts = 32;
    int c = blockIdx.x / parts;
    int part = blockIdx.x % parts;
    const int DW_PER_CH = NPIX / 2;
    int chunk = DW_PER_CH / parts;
    int start = part * chunk;
    const unsigned* r32 = (const unsigned*)raw;
    float s = 0.f, q = 0.f;
    for (int j = start + threadIdx.x; j < start + chunk; j += blockDim.x) {
        int b = j >> 11;
        int dpos = j & 2047;
        unsigned u = r32[((size_t)(b * 64 + c) << 11) + dpos];
        float a = h_lo(u), bb = h_hi(u);
        s += a + bb;
        q += a * a + bb * bb;
    }
    __shared__ float ls[256], lq[256];
    ls[threadIdx.x] = s;
    lq[threadIdx.x] = q;
    __syncthreads();
    for (int st = 128; st > 0; st >>= 1) {
        if (threadIdx.x < st) {
            ls[threadIdx.x] += ls[threadIdx.x + st];
            lq[threadIdx.x] += lq[threadIdx.x + st];
        }
        __syncthreads();
    }
    if (threadIdx.x == 0) {
        atomicAdd(&sums[c], ls[0]);
        atomicAdd(&sums[64 + c], lq[0]);
    }
}

// ---------------------------------------------------------------------------
// Fused stage-4 BN finalize+apply (fp16 raw -> fp32 em, NCHW) + quadrant pool.
// ---------------------------------------------------------------------------
__global__ void bn4_apply_pool(const unsigned short* __restrict__ raw,
                               const float* __restrict__ sums,
                               const float* __restrict__ g4,
                               const float* __restrict__ b4,
                               float* __restrict__ em,
                               float* __restrict__ pw) {
    int bc = blockIdx.x;
    int c = bc & 63;
    int t = threadIdx.x;
    __shared__ float lsc, lsh;
    __shared__ float qs[4];
    if (t == 0) {
        const float invN = 1.f / (float)NPIX;
        float mean = sums[c] * invN;
        float var = sums[64 + c] * invN - mean * mean;
        float sc = g4[c] * rsqrtf(var + BN_EPS);
        lsc = sc;
        lsh = b4[c] - mean * sc;
    }
    if (t < 4) qs[t] = 0.f;
    __syncthreads();
    float sc = lsc, sh = lsh;
    const unsigned* rb = (const unsigned*)(raw + ((size_t)bc << 12));
    float* base = em + ((size_t)bc << 12);
    int pos = t * 16;
    int quad = ((pos >= 2048) ? 2 : 0) + ((pos & 63) >> 5);
    float s = 0.f;
#pragma unroll
    for (int gg = 0; gg < 2; ++gg) {
        uint4 u = *(const uint4*)(rb + (pos >> 1) + gg * 4);
        float f0 = fmaf(h_lo(u.x), sc, sh), f1 = fmaf(h_hi(u.x), sc, sh);
        float f2 = fmaf(h_lo(u.y), sc, sh), f3 = fmaf(h_hi(u.y), sc, sh);
        float f4 = fmaf(h_lo(u.z), sc, sh), f5 = fmaf(h_hi(u.z), sc, sh);
        float f6 = fmaf(h_lo(u.w), sc, sh), f7 = fmaf(h_hi(u.w), sc, sh);
        *(float4*)(base + pos + gg * 8) = make_float4(f0, f1, f2, f3);
        *(float4*)(base + pos + gg * 8 + 4) = make_float4(f4, f5, f6, f7);
        s += f0 + f1 + f2 + f3 + f4 + f5 + f6 + f7;
    }
    atomicAdd(&qs[quad], s);
    __syncthreads();
    if (t < 4) pw[bc * 4 + t] = qs[t] * (1.f / 1024.f);
}

__global__ void fc_softmax_kernel(const float* __restrict__ pw,
                                  const float* __restrict__ fw,
                                  const float* __restrict__ fb,
                                  float* __restrict__ out) {
    int b = blockIdx.x;
    int t = threadIdx.x;
    __shared__ float logits[10];
    if (t < 10) {
        float acc = fb[t];
        const float* p = pw + b * 256;
        for (int q = 0; q < 256; ++q) acc = fmaf(p[q], fw[t * 256 + q], acc);
        logits[t] = acc;
    }
    __syncthreads();
    if (t == 0) {
        float m = -1e30f;
        for (int q = 0; q < 10; ++q) m = fmaxf(m, logits[q]);
        float e[10], sum = 0.f;
        for (int q = 0; q < 10; ++q) { e[q] = expf(logits[q] - m); sum += e[q]; }
        float inv = 1.f / sum;
        for (int q = 0; q < 10; ++q) out[b * 10 + q] = e[q] * inv;
    }
}

// ---------------------------------------------------------------------------
extern "C" void kernel_launch(void* const* d_in, const int* in_sizes, int n_in,
                              void* d_out, int out_size, void* d_ws, size_t ws_size,
                              hipStream_t stream) {
    (void)in_sizes; (void)n_in; (void)out_size; (void)ws_size;

    const float* x   = (const float*)d_in[0];
    const float* w1  = (const float*)d_in[1];
    const float* g1  = (const float*)d_in[2];
    const float* b1  = (const float*)d_in[3];
    const float* w2  = (const float*)d_in[4];
    const float* bc2 = (const float*)d_in[5];
    const float* g2  = (const float*)d_in[6];
    const float* b2  = (const float*)d_in[7];
    const float* w3  = (const float*)d_in[8];
    const float* wd1 = (const float*)d_in[9];
    const float* g3  = (const float*)d_in[10];
    const float* b3  = (const float*)d_in[11];
    const float* w4  = (const float*)d_in[12];
    const float* bc4 = (const float*)d_in[13];
    const float* wd2 = (const float*)d_in[14];
    const float* g4  = (const float*)d_in[15];
    const float* b4  = (const float*)d_in[16];
    const float* fw  = (const float*)d_in[17];
    const float* fb  = (const float*)d_in[18];

    float* out = (float*)d_out;
    float* softout = out;                         // 64*10
    float* em = out + 640;                        // 64ch NCHW fp32

    float* ws = (float*)d_ws;
    float* h1 = ws;                                                  // NHWC  8ch fp32
    unsigned short* h2b = (unsigned short*)(h1 + (size_t)2097152);   // NHWC 20ch bf16
    unsigned short* h3b = h2b + (size_t)5242880;                     // NHWC 40ch bf16
    unsigned* offu = (unsigned*)(h3b + (size_t)10485760);            // fp16 pair planes
    unsigned short* emraw = (unsigned short*)(offu + (size_t)9 * NPIX); // fp16 NCHW raw em
    float* sums1 = (float*)(emraw + (size_t)16777216);               // 4 stages' sums
    float* sums2 = sums1 + 128;
    float* sums3 = sums2 + 128;
    float* sums4 = sums3 + 128;
    float* pw = sums4 + 128;                      // 64*256

    dim3 blk(TPB);
    dim3 gpix(BATCH * PIXBLK);                    // 512

    hipMemsetAsync(sums1, 0, 4 * 128 * sizeof(float), stream);

    // stage 1: conv1 (NCHW fp32 in -> NHWC fp32) + relu + fused bn1 stats
    conv3x3_k<3, 8, true, false, false, true, false, 0, true>
        <<<gpix, blk, 0, stream>>>(x, w1, nullptr, nullptr, nullptr, nullptr, h1, sums1);

    // stage 2: conv2 (+bias, bn1 affine in-prologue) + relu -> h2 bf16 + bn2 stats
    conv3x3_k<8, 20, true, true, true, false, false, 1, true>
        <<<gpix, blk, 0, stream>>>(h1, w2, bc2, sums1, g1, b1, h2b, sums2);

    // stage 3: offset conv -> fp16 planes; deform1 -> h3 bf16 + fused bn3 stats
    conv3x3_k<20, 18, false, false, true, false, true, 2, false>
        <<<gpix, blk, 0, stream>>>(h2b, w3, nullptr, sums2, g2, b2, offu, nullptr);
    deform_k<20, 40, 20, 2>
        <<<dim3(BATCH * PIXBLK * 2), blk, 0, stream>>>(h2b, offu, wd1, sums2, g2, b2, h3b, sums3);

    // stage 4: offset conv2 -> fp16 planes; deform2 (lane-paired sample-once)
    conv3x3_k<40, 18, false, true, true, false, true, 2, false>
        <<<gpix, blk, 0, stream>>>(h3b, w4, bc4, sums3, g3, b3, offu, nullptr);
    deform2_pair_k<<<dim3(1024), blk, 0, stream>>>(h3b, offu, wd2, sums3, g3, b3, emraw);
    bn_partial_nchw_h16<<<64 * 32, 256, 0, stream>>>(emraw, sums4);

    // fused bn4 finalize+apply + quadrant pool; FC + softmax
    bn4_apply_pool<<<64 * 64, 256, 0, stream>>>(emraw, sums4, g4, b4, em, pw);
    fc_softmax_kernel<<<64, 64, 0, stream>>>(pw, fw, fb, softout);
}

// Round 16
// 565.173 us; speedup vs baseline: 1.0155x; 1.0155x over previous
//
#include <hip/hip_runtime.h>

#define IMW 64
#define HW 4096
#define BATCH 64
#define NPIX (BATCH * HW)   // 262144
#define TPB 512             // threads per spatial block
#define PIXBLK 8            // pixel-blocks per image (4096/512)
#define BN_EPS 1e-5f

// ---------------- bf16 helpers (manual, RNE) ----------------
__device__ inline float bfbits(unsigned int hi16) {
    union { unsigned int i; float f; } v; v.i = hi16; return v.f;
}
__device__ inline float bf_lo(unsigned int u) { return bfbits(u << 16); }
__device__ inline float bf_hi(unsigned int u) { return bfbits(u & 0xffff0000u); }
__device__ inline unsigned short f2bf(float f) {
    union { float f; unsigned int i; } v; v.f = f;
    unsigned int i = v.i;
    i += 0x7fff + ((i >> 16) & 1);
    return (unsigned short)(i >> 16);
}

// ---------------- fp16 helpers ----------------
__device__ inline unsigned pack_h2(float a, float b) {
    union { unsigned u; _Float16 h[2]; } v;
    v.h[0] = (_Float16)a;
    v.h[1] = (_Float16)b;
    return v.u;
}
__device__ inline float h_lo(unsigned u) {
    union { unsigned u; _Float16 h[2]; } v; v.u = u; return (float)v.h[0];
}
__device__ inline float h_hi(unsigned u) {
    union { unsigned u; _Float16 h[2]; } v; v.u = u; return (float)v.h[1];
}
__device__ inline unsigned short f2h(float f) {
    union { _Float16 h; unsigned short u; } v; v.h = (_Float16)f; return v.u;
}

// ---------------------------------------------------------------------------
// XCD-pinned swizzle (verified R3: FETCH 2.4GB -> 455MB). XCD = lin & 7 owns
// images [8*xcd, 8*xcd+8); all pixel/co blocks of an image on one XCD.
// ---------------------------------------------------------------------------
template <int CO_BLOCKS>
__device__ inline void swz(int lin, int& img, int& xblk, int& cob) {
    const int per_img = PIXBLK * CO_BLOCKS;
    int xcd = lin & 7;
    int s = lin >> 3;
    img = xcd * 8 + s / per_img;
    int r = s % per_img;
    cob = r / PIXBLK;
    xblk = r % PIXBLK;
}

// ---------------------------------------------------------------------------
// Direct 3x3 conv, pad=1. NHWC activations (stage-1 input NCHW fp32).
// IN_BF16: bf16 NHWC input. OUT_MODE: 0 = fp32 NHWC, 1 = bf16 NHWC packed,
// 2 = fp16 dword-planes [tap][pixel] (for offsets, COUT=18 -> 9 planes).
// FUSE_BN: per-channel sum/sumsq fused in epilogue (winner on convs — R12).
// AFF: input BN affine computed IN-PROLOGUE from raw sums+g+b (R14).
// R5/R8/R9/R10/R15 LESSON: at TPB=512 the allocator pins these bodies to 64
// arch-VGPRs; any live set beyond ~60 regs spills to scratch.
// ---------------------------------------------------------------------------
template <int CIN, int COUT, bool RELU, bool BIAS, bool AFF, bool IN_NCHW,
          bool IN_BF16, int OUT_MODE, bool FUSE_BN>
__global__ void conv3x3_k(const void* __restrict__ in_,
                          const float* __restrict__ w,
                          const float* __restrict__ bias,
                          const float* __restrict__ isums,   // producer sums [2*CIN]
                          const float* __restrict__ ig,      // producer gamma
                          const float* __restrict__ ib_,     // producer beta
                          void* __restrict__ out_,
                          float* __restrict__ bnsums) {
    __shared__ float lw[9 * CIN * COUT];
    __shared__ float lb[COUT];
    __shared__ float lsc[CIN];
    __shared__ float lsh[CIN];
    __shared__ float bnacc[FUSE_BN ? 2 * COUT : 1];

    for (int dst = threadIdx.x; dst < 9 * CIN * COUT; dst += blockDim.x) {
        int co = dst % COUT;
        int kci = dst / COUT;
        int k = kci / CIN;
        int ci = kci % CIN;
        lw[dst] = w[(size_t)co * (CIN * 9) + ci * 9 + k];
    }
    if (threadIdx.x < COUT) lb[threadIdx.x] = BIAS ? bias[threadIdx.x] : 0.f;
    if (AFF && threadIdx.x < CIN) {
        const float invN = 1.f / (float)NPIX;
        float mean = isums[threadIdx.x] * invN;
        float var = isums[CIN + threadIdx.x] * invN - mean * mean;
        float sc = ig[threadIdx.x] * rsqrtf(var + BN_EPS);
        lsc[threadIdx.x] = sc;
        lsh[threadIdx.x] = ib_[threadIdx.x] - mean * sc;
    }
    if (FUSE_BN && threadIdx.x < 2 * COUT) bnacc[threadIdx.x] = 0.f;
    __syncthreads();

    int img, xblk, cob;
    swz<1>(blockIdx.x, img, xblk, cob);
    int b = img;
    int pos = xblk * TPB + threadIdx.x;
    int p = (b << 12) + pos;
    int y = pos >> 6;
    int x = pos & 63;

    float acc[COUT];
#pragma unroll
    for (int co = 0; co < COUT; ++co) acc[co] = lb[co];

#pragma unroll 1
    for (int k = 0; k < 9; ++k) {
        int ky = k / 3, kx = k - ky * 3;
        int yy = y + ky - 1, xx = x + kx - 1;
        if (yy < 0 || yy >= IMW || xx < 0 || xx >= IMW) continue;

        float vin[CIN];
        if constexpr (IN_NCHW) {
            const float* ip = (const float*)in_;
#pragma unroll
            for (int ci = 0; ci < CIN; ++ci)
                vin[ci] = ip[((size_t)(b * CIN + ci) << 12) + yy * IMW + xx];
        } else if constexpr (!IN_BF16) {
            const float* ip = (const float*)in_ + ((size_t)((b << 12) + yy * IMW + xx)) * CIN;
#pragma unroll
            for (int c4 = 0; c4 < CIN / 4; ++c4) {
                float4 v = *(const float4*)(ip + c4 * 4);
                vin[c4 * 4 + 0] = v.x;
                vin[c4 * 4 + 1] = v.y;
                vin[c4 * 4 + 2] = v.z;
                vin[c4 * 4 + 3] = v.w;
            }
        } else if constexpr (CIN % 8 == 0) {
            const uint4* ip = (const uint4*)((const unsigned short*)in_ +
                                             ((size_t)((b << 12) + yy * IMW + xx)) * CIN);
#pragma unroll
            for (int c8 = 0; c8 < CIN / 8; ++c8) {
                uint4 u = ip[c8];
                vin[c8 * 8 + 0] = bf_lo(u.x); vin[c8 * 8 + 1] = bf_hi(u.x);
                vin[c8 * 8 + 2] = bf_lo(u.y); vin[c8 * 8 + 3] = bf_hi(u.y);
                vin[c8 * 8 + 4] = bf_lo(u.z); vin[c8 * 8 + 5] = bf_hi(u.z);
                vin[c8 * 8 + 6] = bf_lo(u.w); vin[c8 * 8 + 7] = bf_hi(u.w);
            }
        } else {
            const uint2* ip = (const uint2*)((const unsigned short*)in_ +
                                             ((size_t)((b << 12) + yy * IMW + xx)) * CIN);
#pragma unroll
            for (int c4 = 0; c4 < CIN / 4; ++c4) {
                uint2 u = ip[c4];
                vin[c4 * 4 + 0] = bf_lo(u.x); vin[c4 * 4 + 1] = bf_hi(u.x);
                vin[c4 * 4 + 2] = bf_lo(u.y); vin[c4 * 4 + 3] = bf_hi(u.y);
            }
        }
        if constexpr (AFF) {
#pragma unroll
            for (int ci = 0; ci < CIN; ++ci)
                vin[ci] = fmaf(vin[ci], lsc[ci], lsh[ci]);
        }
#pragma unroll
        for (int ci = 0; ci < CIN; ++ci) {
            float s = vin[ci];
            const float* wr = &lw[(k * CIN + ci) * COUT];
#pragma unroll
            for (int co = 0; co < COUT; ++co)
                acc[co] = fmaf(wr[co], s, acc[co]);
        }
    }

    if (RELU) {
#pragma unroll
        for (int co = 0; co < COUT; ++co) acc[co] = fmaxf(acc[co], 0.f);
    }

    if constexpr (FUSE_BN) {
#pragma unroll
        for (int co = 0; co < COUT; ++co) {
            float s = acc[co];
            float q = s * s;
#pragma unroll
            for (int off = 32; off; off >>= 1) {
                s += __shfl_down(s, off, 64);
                q += __shfl_down(q, off, 64);
            }
            if ((threadIdx.x & 63) == 0) {
                atomicAdd(&bnacc[co], s);
                atomicAdd(&bnacc[COUT + co], q);
            }
        }
    }

    if constexpr (OUT_MODE == 2) {
        // fp16 pair planes: plane j holds channels (2j, 2j+1) at [j*NPIX + p]
        unsigned* o = (unsigned*)out_;
#pragma unroll
        for (int i = 0; i < COUT / 2; ++i)
            o[(size_t)i * NPIX + p] = pack_h2(acc[2 * i], acc[2 * i + 1]);
    } else if constexpr (OUT_MODE == 1) {
        unsigned int us[COUT / 2];
#pragma unroll
        for (int i = 0; i < COUT / 2; ++i)
            us[i] = (unsigned int)f2bf(acc[2 * i]) | ((unsigned int)f2bf(acc[2 * i + 1]) << 16);
        uint2* o2 = (uint2*)((unsigned short*)out_ + (size_t)p * COUT);
#pragma unroll
        for (int i = 0; i < COUT / 4; ++i)
            o2[i] = make_uint2(us[2 * i], us[2 * i + 1]);
    } else {
        float* op = (float*)out_ + (size_t)p * COUT;
        if constexpr (COUT % 4 == 0) {
#pragma unroll
            for (int c4 = 0; c4 < COUT / 4; ++c4)
                *(float4*)(op + c4 * 4) =
                    make_float4(acc[c4 * 4], acc[c4 * 4 + 1], acc[c4 * 4 + 2], acc[c4 * 4 + 3]);
        } else {
#pragma unroll
            for (int c2 = 0; c2 < COUT / 2; ++c2)
                *(float2*)(op + c2 * 2) = make_float2(acc[c2 * 2], acc[c2 * 2 + 1]);
        }
    }

    if constexpr (FUSE_BN) {
        __syncthreads();
        if (threadIdx.x < 2 * COUT)
            atomicAdd(&bnsums[threadIdx.x], bnacc[threadIdx.x]);
    }
}

// ---------------------------------------------------------------------------
// Deformable conv 3x3, bf16 NHWC input + fp16 plane offsets (hoisted loads).
// Input BN affine computed in-prologue from raw sums (R14), applied via the
// wsum trick. OUT_NCHW: fp16 raw em planes; else bf16 NHWC packed (h3).
// PERTAP: double-buffered per-tap weight staging -> 4 blocks/CU.
// FUSE: fused BN stats epilogue — deform1 only (R12: loser on deform2).
// R7-proven FINAL config for deform2: COUT_BLK=32 / CO_BLOCKS=2 (acc[32]
// fits the 64-VGPR wall; all sample-once variants failed: R8/R9/R10/R15).
// ---------------------------------------------------------------------------
template <int CIN, int COUT_TOT, int COUT_BLK, int CO_BLOCKS, bool OUT_NCHW,
          bool PERTAP, bool FUSE>
__global__ void deform_k(const void* __restrict__ in_,
                         const unsigned* __restrict__ off,   // fp16 pair planes
                         const float* __restrict__ w,
                         const float* __restrict__ isums,    // producer sums [2*CIN]
                         const float* __restrict__ ig,
                         const float* __restrict__ ib_,
                         void* __restrict__ out_,
                         float* __restrict__ bnsums) {
    constexpr int WSLICE = CIN * COUT_BLK;          // weights per tap
    constexpr int LWSZ = PERTAP ? 2 * WSLICE : 9 * WSLICE;
    __shared__ float lw[LWSZ];
    __shared__ float lsc[CIN];
    __shared__ float lsh[CIN];
    __shared__ float bnacc[FUSE ? 2 * COUT_BLK : 1];

    int img, xblk, cob;
    swz<CO_BLOCKS>(blockIdx.x, img, xblk, cob);
    int co_base = cob * COUT_BLK;

    if (threadIdx.x < CIN) {
        const float invN = 1.f / (float)NPIX;
        float mean = isums[threadIdx.x] * invN;
        float var = isums[CIN + threadIdx.x] * invN - mean * mean;
        float sc = ig[threadIdx.x] * rsqrtf(var + BN_EPS);
        lsc[threadIdx.x] = sc;
        lsh[threadIdx.x] = ib_[threadIdx.x] - mean * sc;
    }
    if (FUSE && threadIdx.x < 2 * COUT_BLK) bnacc[threadIdx.x] = 0.f;

    // per-thread weight-source pointer: co fixed, ci advances by TPB/COUT_BLK per j
    const float* wsrc = nullptr;
    if constexpr (PERTAP) {
        wsrc = w + (size_t)(co_base + (threadIdx.x & (COUT_BLK - 1))) * (CIN * 9) +
               (threadIdx.x / COUT_BLK) * 9;
    } else {
        for (int dst = threadIdx.x; dst < 9 * WSLICE; dst += blockDim.x) {
            int co = dst % COUT_BLK;
            int kci = dst / COUT_BLK;
            int k = kci / CIN;
            int ci = kci % CIN;
            lw[dst] = w[(size_t)(co_base + co) * (CIN * 9) + ci * 9 + k];
        }
    }

    constexpr int NFULL = WSLICE / TPB;             // full rounds of TPB
    constexpr int REM = WSLICE - NFULL * TPB;       // remainder threads
    constexpr int CISTEP = TPB / COUT_BLK;          // ci advance per round

    auto stage_tap = [&](int k, int buf) {
        if constexpr (PERTAP) {
            const float* src = wsrc + k;
            float* d = lw + buf * WSLICE + threadIdx.x;
#pragma unroll
            for (int j = 0; j < NFULL; ++j)
                d[j * TPB] = src[(size_t)j * CISTEP * 9];
            if (REM > 0 && threadIdx.x < REM)
                d[NFULL * TPB] = src[(size_t)NFULL * CISTEP * 9];
        }
    };

    if constexpr (PERTAP) stage_tap(0, 0);
    __syncthreads();

    int b = img;
    int pos = xblk * TPB + threadIdx.x;
    int p = (b << 12) + pos;
    int y = pos >> 6;
    int x = pos & 63;

    float acc[COUT_BLK];
#pragma unroll
    for (int co = 0; co < COUT_BLK; ++co) acc[co] = 0.f;

    // hoist all 9 tap offsets (independent coalesced dword loads)
    unsigned od[9];
#pragma unroll
    for (int j = 0; j < 9; ++j) od[j] = off[(size_t)j * NPIX + p];

    const unsigned short* ib = (const unsigned short*)in_ + (size_t)b * HW * CIN;

#pragma unroll 1
    for (int k = 0; k < 9; ++k) {
        if constexpr (PERTAP) {
            if (k < 8) stage_tap(k + 1, (k + 1) & 1);
        }
        const int kbase = PERTAP ? (k & 1) * CIN : k * CIN;

        int ky = k / 3, kx = k - ky * 3;
        float py = (float)(y + ky - 1) + h_lo(od[k]);
        float px = (float)(x + kx - 1) + h_hi(od[k]);
        float fy = floorf(py), fx = floorf(px);
        float wy = py - fy, wx = px - fx;
        int y0 = (int)fy, x0 = (int)fx;
        int y1 = y0 + 1, x1 = x0 + 1;
        bool vy0 = (unsigned)y0 < (unsigned)IMW;
        bool vy1 = (unsigned)y1 < (unsigned)IMW;
        bool vx0 = (unsigned)x0 < (unsigned)IMW;
        bool vx1 = (unsigned)x1 < (unsigned)IMW;
        int cy0 = min(max(y0, 0), IMW - 1), cy1 = min(max(y1, 0), IMW - 1);
        int cx0 = min(max(x0, 0), IMW - 1), cx1 = min(max(x1, 0), IMW - 1);
        float w00 = (1.f - wy) * (1.f - wx) * ((vy0 & vx0) ? 1.f : 0.f);
        float w01 = (1.f - wy) * wx * ((vy0 & vx1) ? 1.f : 0.f);
        float w10 = wy * (1.f - wx) * ((vy1 & vx0) ? 1.f : 0.f);
        float w11 = wy * wx * ((vy1 & vx1) ? 1.f : 0.f);
        float wsum = w00 + w01 + w10 + w11;

        if constexpr (CIN % 8 == 0) {
            const uint4* q00 = (const uint4*)(ib + (size_t)(cy0 * IMW + cx0) * CIN);
            const uint4* q01 = (const uint4*)(ib + (size_t)(cy0 * IMW + cx1) * CIN);
            const uint4* q10 = (const uint4*)(ib + (size_t)(cy1 * IMW + cx0) * CIN);
            const uint4* q11 = (const uint4*)(ib + (size_t)(cy1 * IMW + cx1) * CIN);
#pragma unroll 1
            for (int c8 = 0; c8 < CIN / 8; ++c8) {
                uint4 a = q00[c8], bq = q01[c8], c = q10[c8], d = q11[c8];
#pragma unroll
                for (int h = 0; h < 4; ++h) {
                    unsigned int ua = (&a.x)[h], ub = (&bq.x)[h];
                    unsigned int uc = (&c.x)[h], ud = (&d.x)[h];
                    int ci0 = c8 * 8 + h * 2;
                    float r0 = w00 * bf_lo(ua) + w01 * bf_lo(ub) +
                               w10 * bf_lo(uc) + w11 * bf_lo(ud);
                    float r1 = w00 * bf_hi(ua) + w01 * bf_hi(ub) +
                               w10 * bf_hi(uc) + w11 * bf_hi(ud);
                    float s0 = fmaf(r0, lsc[ci0], lsh[ci0] * wsum);
                    float s1 = fmaf(r1, lsc[ci0 + 1], lsh[ci0 + 1] * wsum);
                    const float* wr0 = &lw[(kbase + ci0) * COUT_BLK];
                    const float* wr1 = &lw[(kbase + ci0 + 1) * COUT_BLK];
#pragma unroll
                    for (int co = 0; co < COUT_BLK; ++co)
                        acc[co] = fmaf(wr0[co], s0, acc[co]);
#pragma unroll
                    for (int co = 0; co < COUT_BLK; ++co)
                        acc[co] = fmaf(wr1[co], s1, acc[co]);
                }
            }
        } else {
            const uint2* q00 = (const uint2*)(ib + (size_t)(cy0 * IMW + cx0) * CIN);
            const uint2* q01 = (const uint2*)(ib + (size_t)(cy0 * IMW + cx1) * CIN);
            const uint2* q10 = (const uint2*)(ib + (size_t)(cy1 * IMW + cx0) * CIN);
            const uint2* q11 = (const uint2*)(ib + (size_t)(cy1 * IMW + cx1) * CIN);
#pragma unroll
            for (int c4 = 0; c4 < CIN / 4; ++c4) {
                uint2 a = q00[c4], bq = q01[c4], c = q10[c4], d = q11[c4];
#pragma unroll
                for (int h = 0; h < 2; ++h) {
                    unsigned int ua = (&a.x)[h], ub = (&bq.x)[h];
                    unsigned int uc = (&c.x)[h], ud = (&d.x)[h];
                    int ci0 = c4 * 4 + h * 2;
                    float r0 = w00 * bf_lo(ua) + w01 * bf_lo(ub) +
                               w10 * bf_lo(uc) + w11 * bf_lo(ud);
                    float r1 = w00 * bf_hi(ua) + w01 * bf_hi(ub) +
                               w10 * bf_hi(uc) + w11 * bf_hi(ud);
                    float s0 = fmaf(r0, lsc[ci0], lsh[ci0] * wsum);
                    float s1 = fmaf(r1, lsc[ci0 + 1], lsh[ci0 + 1] * wsum);
                    const float* wr0 = &lw[(kbase + ci0) * COUT_BLK];
                    const float* wr1 = &lw[(kbase + ci0 + 1) * COUT_BLK];
#pragma unroll
                    for (int co = 0; co < COUT_BLK; ++co)
                        acc[co] = fmaf(wr0[co], s0, acc[co]);
#pragma unroll
                    for (int co = 0; co < COUT_BLK; ++co)
                        acc[co] = fmaf(wr1[co], s1, acc[co]);
                }
            }
        }

        if constexpr (PERTAP) __syncthreads();
    }

#pragma unroll
    for (int co = 0; co < COUT_BLK; ++co) acc[co] = fmaxf(acc[co], 0.f);

    if constexpr (FUSE) {
#pragma unroll
        for (int co = 0; co < COUT_BLK; ++co) {
            float s = acc[co];
            float q = s * s;
#pragma unroll
            for (int off2 = 32; off2; off2 >>= 1) {
                s += __shfl_down(s, off2, 64);
                q += __shfl_down(q, off2, 64);
            }
            if ((threadIdx.x & 63) == 0) {
                atomicAdd(&bnacc[co], s);
                atomicAdd(&bnacc[COUT_BLK + co], q);
            }
        }
    }

    if constexpr (OUT_NCHW) {
        // fp16 raw em planes: halves write + later read traffic (R12-verified)
        unsigned short* o = (unsigned short*)out_;
#pragma unroll
        for (int co = 0; co < COUT_BLK; ++co)
            __builtin_nontemporal_store(f2h(acc[co]),
                &o[((size_t)(b * COUT_TOT + co_base + co) << 12) + pos]);
    } else {
        unsigned int us[COUT_BLK / 2];
#pragma unroll
        for (int i = 0; i < COUT_BLK / 2; ++i)
            us[i] = (unsigned int)f2bf(acc[2 * i]) | ((unsigned int)f2bf(acc[2 * i + 1]) << 16);
        unsigned short* ob = (unsigned short*)out_ + (size_t)p * COUT_TOT + co_base;
        if constexpr (COUT_BLK % 8 == 0) {
            uint4* o4 = (uint4*)ob;
#pragma unroll
            for (int i = 0; i < COUT_BLK / 8; ++i)
                o4[i] = make_uint4(us[4 * i], us[4 * i + 1], us[4 * i + 2], us[4 * i + 3]);
        } else {
            uint2* o2 = (uint2*)ob;
#pragma unroll
            for (int i = 0; i < COUT_BLK / 4; ++i)
                o2[i] = make_uint2(us[2 * i], us[2 * i + 1]);
        }
    }

    if constexpr (FUSE) {
        __syncthreads();
        if (threadIdx.x < COUT_BLK)
            atomicAdd(&bnsums[co_base + threadIdx.x], bnacc[threadIdx.x]);
        else if (threadIdx.x < 2 * COUT_BLK)
            atomicAdd(&bnsums[COUT_TOT + co_base + (threadIdx.x - COUT_BLK)],
                      bnacc[threadIdx.x]);
    }
}

// ---------------------------------------------------------------------------
// BN stats over fp16 NCHW raw em (dword-vectorized). 64 ch x 32 parts.
// ---------------------------------------------------------------------------
__global__ void bn_partial_nchw_h16(const unsigned short* __restrict__ raw,
                                    float* __restrict__ sums) {
    const int parts = 32;
    int c = blockIdx.x / parts;
    int part = blockIdx.x % parts;
    const int DW_PER_CH = NPIX / 2;           // 131072 dwords per channel
    int chunk = DW_PER_CH / parts;            // 4096
    int start = part * chunk;
    const unsigned* r32 = (const unsigned*)raw;
    float s = 0.f, q = 0.f;
    for (int j = start + threadIdx.x; j < start + chunk; j += blockDim.x) {
        int b = j >> 11;                      // 2048 dwords per plane
        int dpos = j & 2047;
        unsigned u = r32[((size_t)(b * 64 + c) << 11) + dpos];
        float a = h_lo(u), bb = h_hi(u);
        s += a + bb;
        q += a * a + bb * bb;
    }
    __shared__ float ls[256], lq[256];
    ls[threadIdx.x] = s;
    lq[threadIdx.x] = q;
    __syncthreads();
    for (int st = 128; st > 0; st >>= 1) {
        if (threadIdx.x < st) {
            ls[threadIdx.x] += ls[threadIdx.x + st];
            lq[threadIdx.x] += lq[threadIdx.x + st];
        }
        __syncthreads();
    }
    if (threadIdx.x == 0) {
        atomicAdd(&sums[c], ls[0]);
        atomicAdd(&sums[64 + c], lq[0]);
    }
}

// ---------------------------------------------------------------------------
// Fused stage-4 BN finalize+apply (fp16 raw -> fp32 em, NCHW) + quadrant pool.
// Thread 0 computes this block's channel scale/shift from raw sums (R14).
// ---------------------------------------------------------------------------
__global__ void bn4_apply_pool(const unsigned short* __restrict__ raw,
                               const float* __restrict__ sums,
                               const float* __restrict__ g4,
                               const float* __restrict__ b4,
                               float* __restrict__ em,
                               float* __restrict__ pw) {
    int bc = blockIdx.x;
    int c = bc & 63;
    int t = threadIdx.x;
    __shared__ float lsc, lsh;
    __shared__ float qs[4];
    if (t == 0) {
        const float invN = 1.f / (float)NPIX;
        float mean = sums[c] * invN;
        float var = sums[64 + c] * invN - mean * mean;
        float sc = g4[c] * rsqrtf(var + BN_EPS);
        lsc = sc;
        lsh = b4[c] - mean * sc;
    }
    if (t < 4) qs[t] = 0.f;
    __syncthreads();
    float sc = lsc, sh = lsh;
    const unsigned* rb = (const unsigned*)(raw + ((size_t)bc << 12));
    float* base = em + ((size_t)bc << 12);
    int pos = t * 16;
    int quad = ((pos >= 2048) ? 2 : 0) + ((pos & 63) >> 5);
    float s = 0.f;
#pragma unroll
    for (int gg = 0; gg < 2; ++gg) {
        uint4 u = *(const uint4*)(rb + (pos >> 1) + gg * 4);
        float f0 = fmaf(h_lo(u.x), sc, sh), f1 = fmaf(h_hi(u.x), sc, sh);
        float f2 = fmaf(h_lo(u.y), sc, sh), f3 = fmaf(h_hi(u.y), sc, sh);
        float f4 = fmaf(h_lo(u.z), sc, sh), f5 = fmaf(h_hi(u.z), sc, sh);
        float f6 = fmaf(h_lo(u.w), sc, sh), f7 = fmaf(h_hi(u.w), sc, sh);
        *(float4*)(base + pos + gg * 8) = make_float4(f0, f1, f2, f3);
        *(float4*)(base + pos + gg * 8 + 4) = make_float4(f4, f5, f6, f7);
        s += f0 + f1 + f2 + f3 + f4 + f5 + f6 + f7;
    }
    atomicAdd(&qs[quad], s);
    __syncthreads();
    if (t < 4) pw[bc * 4 + t] = qs[t] * (1.f / 1024.f);
}

__global__ void fc_softmax_kernel(const float* __restrict__ pw,
                                  const float* __restrict__ fw,
                                  const float* __restrict__ fb,
                                  float* __restrict__ out) {
    int b = blockIdx.x;
    int t = threadIdx.x;
    __shared__ float logits[10];
    if (t < 10) {
        float acc = fb[t];
        const float* p = pw + b * 256;
        for (int q = 0; q < 256; ++q) acc = fmaf(p[q], fw[t * 256 + q], acc);
        logits[t] = acc;
    }
    __syncthreads();
    if (t == 0) {
        float m = -1e30f;
        for (int q = 0; q < 10; ++q) m = fmaxf(m, logits[q]);
        float e[10], sum = 0.f;
        for (int q = 0; q < 10; ++q) { e[q] = expf(logits[q] - m); sum += e[q]; }
        float inv = 1.f / sum;
        for (int q = 0; q < 10; ++q) out[b * 10 + q] = e[q] * inv;
    }
}

// ---------------------------------------------------------------------------
extern "C" void kernel_launch(void* const* d_in, const int* in_sizes, int n_in,
                              void* d_out, int out_size, void* d_ws, size_t ws_size,
                              hipStream_t stream) {
    (void)in_sizes; (void)n_in; (void)out_size; (void)ws_size;

    const float* x   = (const float*)d_in[0];
    const float* w1  = (const float*)d_in[1];
    const float* g1  = (const float*)d_in[2];
    const float* b1  = (const float*)d_in[3];
    const float* w2  = (const float*)d_in[4];
    const float* bc2 = (const float*)d_in[5];
    const float* g2  = (const float*)d_in[6];
    const float* b2  = (const float*)d_in[7];
    const float* w3  = (const float*)d_in[8];
    const float* wd1 = (const float*)d_in[9];
    const float* g3  = (const float*)d_in[10];
    const float* b3  = (const float*)d_in[11];
    const float* w4  = (const float*)d_in[12];
    const float* bc4 = (const float*)d_in[13];
    const float* wd2 = (const float*)d_in[14];
    const float* g4  = (const float*)d_in[15];
    const float* b4  = (const float*)d_in[16];
    const float* fw  = (const float*)d_in[17];
    const float* fb  = (const float*)d_in[18];

    float* out = (float*)d_out;
    float* softout = out;                         // 64*10
    float* em = out + 640;                        // 64ch NCHW fp32

    float* ws = (float*)d_ws;
    float* h1 = ws;                                                  // NHWC  8ch fp32: 2,097,152 floats
    unsigned short* h2b = (unsigned short*)(h1 + (size_t)2097152);   // NHWC 20ch bf16: 5,242,880 shorts
    unsigned short* h3b = h2b + (size_t)5242880;                     // NHWC 40ch bf16: 10,485,760 shorts
    unsigned* offu = (unsigned*)(h3b + (size_t)10485760);            // fp16 pair planes: 9*NPIX uints
    unsigned short* emraw = (unsigned short*)(offu + (size_t)9 * NPIX); // fp16 NCHW raw em
    float* sums1 = (float*)(emraw + (size_t)16777216);               // 4 stages' sums: 4*128
    float* sums2 = sums1 + 128;
    float* sums3 = sums2 + 128;
    float* sums4 = sums3 + 128;
    float* pw = sums4 + 128;                      // 64*256

    dim3 blk(TPB);
    dim3 gpix(BATCH * PIXBLK);                    // 512

    // zero all four sums regions once
    hipMemsetAsync(sums1, 0, 4 * 128 * sizeof(float), stream);

    // stage 1: conv1 (NCHW fp32 in -> NHWC fp32) + relu + fused bn1 stats
    conv3x3_k<3, 8, true, false, false, true, false, 0, true>
        <<<gpix, blk, 0, stream>>>(x, w1, nullptr, nullptr, nullptr, nullptr, h1, sums1);

    // stage 2: conv2 (+bias, bn1 affine in-prologue) + relu -> h2 bf16 + bn2 stats
    conv3x3_k<8, 20, true, true, true, false, false, 1, true>
        <<<gpix, blk, 0, stream>>>(h1, w2, bc2, sums1, g1, b1, h2b, sums2);

    // stage 3: offset conv (bn2 affine in-prologue) -> fp16 planes;
    //          deform1 (bn2 affine in-prologue) -> h3 bf16 + fused bn3 stats
    conv3x3_k<20, 18, false, false, true, false, true, 2, false>
        <<<gpix, blk, 0, stream>>>(h2b, w3, nullptr, sums2, g2, b2, offu, nullptr);
    deform_k<20, 40, 20, 2, false, false, true>
        <<<dim3(BATCH * PIXBLK * 2), blk, 0, stream>>>(h2b, offu, wd1, sums2, g2, b2, h3b, sums3);

    // stage 4: offset conv2 (+bias, bn3 affine in-prologue) -> fp16 planes;
    //          deform2 (R7 config, bn3 affine in-prologue) -> fp16 raw em;
    //          separate fp16 stats pass
    conv3x3_k<40, 18, false, true, true, false, true, 2, false>
        <<<gpix, blk, 0, stream>>>(h3b, w4, bc4, sums3, g3, b3, offu, nullptr);
    deform_k<40, 64, 32, 2, true, true, false>
        <<<dim3(BATCH * PIXBLK * 2), blk, 0, stream>>>(h3b, offu, wd2, sums3, g3, b3, emraw, nullptr);
    bn_partial_nchw_h16<<<64 * 32, 256, 0, stream>>>(emraw, sums4);

    // fused bn4 finalize+apply (fp16 raw -> fp32 em) + quadrant pool; FC+softmax
    bn4_apply_pool<<<64 * 64, 256, 0, stream>>>(emraw, sums4, g4, b4, em, pw);
    fc_softmax_kernel<<<64, 64, 0, stream>>>(pw, fw, fb, softout);
}